// Round 1
// baseline (205.080 us; speedup 1.0000x reference)
//
#include <hip/hip_runtime.h>

#define TT 128
#define CCH 64
#define NTH 512

// LDS layout (float offsets)
//  sx : [128][65]  = 8320 floats  (reused as sy after phase B)
//  sq : [4][2052]  = 8208 floats  (head stride 2052: %32==4 -> conflict-free, %4==0 -> float4 ok)
//  sk : 8208
//  sv : 8208
//  sW : [64][96]   = 6144 floats  (reused as W_proj [64][64])
#define SX_OFF 0
#define SQ_OFF 8320
#define SK_OFF (8320 + 8208)
#define SV_OFF (8320 + 2 * 8208)
#define SW_OFF (8320 + 3 * 8208)
#define LDS_FLOATS (8320 + 3 * 8208 + 6144)   // 39088 floats = 156,352 B <= 163,840

__global__ __launch_bounds__(NTH, 1)
void csa_fused(const float* __restrict__ x, const float* __restrict__ Wa,
               const float* __restrict__ ba, const float* __restrict__ Wp,
               const float* __restrict__ bp, float* __restrict__ out)
{
    extern __shared__ float lds[];
    float* sx = lds + SX_OFF;
    float* sq = lds + SQ_OFF;
    float* sk = lds + SK_OFF;
    float* sv = lds + SV_OFF;
    float* sW = lds + SW_OFF;

    const int b = blockIdx.x;
    const int tid = threadIdx.x;
    const float* __restrict__ xb = x + (size_t)b * (TT * CCH);

    // ---------------- Phase A: load x -> sx[t][65] ----------------
    for (int i = tid; i < (TT * CCH) / 4; i += NTH) {
        float4 v4 = reinterpret_cast<const float4*>(xb)[i];
        int t = i >> 4;              // 16 float4 per 64-col row
        int c = (i & 15) << 2;
        float* dst = sx + t * 65 + c;
        dst[0] = v4.x; dst[1] = v4.y; dst[2] = v4.z; dst[3] = v4.w;
    }
    __syncthreads();

    // ---------------- Phase B: qkv = x @ Wa + ba (two 96-col halves) ----------------
    const int rg  = tid >> 4;   // 0..31 : 4-row group
    const int cgB = tid & 15;   // 0..15 : 6-col group
    for (int half = 0; half < 2; ++half) {
        // stage W_attn[:, half*96 : half*96+96] -> sW[64][96]
        for (int i = tid; i < (64 * 96) / 4; i += NTH) {
            int k = i / 24;            // 24 float4 per row
            int c = (i % 24) << 2;
            float4 w4 = *reinterpret_cast<const float4*>(Wa + k * 192 + half * 96 + c);
            *reinterpret_cast<float4*>(sW + k * 96 + c) = w4;
        }
        __syncthreads();

        float acc[4][6];
        #pragma unroll
        for (int j = 0; j < 6; ++j) {
            float bj = ba[half * 96 + cgB * 6 + j];
            #pragma unroll
            for (int r = 0; r < 4; ++r) acc[r][j] = bj;
        }

        #pragma unroll 4
        for (int k = 0; k < 64; ++k) {
            float xr[4];
            #pragma unroll
            for (int r = 0; r < 4; ++r) xr[r] = sx[(rg * 4 + r) * 65 + k];
            const float* wrow = sW + k * 96 + cgB * 6;
            float2 w01 = *reinterpret_cast<const float2*>(wrow);
            float2 w23 = *reinterpret_cast<const float2*>(wrow + 2);
            float2 w45 = *reinterpret_cast<const float2*>(wrow + 4);
            float wv[6] = {w01.x, w01.y, w23.x, w23.y, w45.x, w45.y};
            #pragma unroll
            for (int r = 0; r < 4; ++r)
                #pragma unroll
                for (int j = 0; j < 6; ++j)
                    acc[r][j] = fmaf(xr[r], wv[j], acc[r][j]);
        }

        // scatter into per-head q/k/v
        #pragma unroll
        for (int r = 0; r < 4; ++r) {
            int row = rg * 4 + r;
            #pragma unroll
            for (int j = 0; j < 6; ++j) {
                int c = half * 96 + cgB * 6 + j;
                int which = c >> 6;            // 0=q 1=k 2=v
                int cc = c & 63;
                float* base = (which == 0) ? sq : ((which == 1) ? sk : sv);
                base[(cc >> 4) * 2052 + row * 16 + (cc & 15)] = acc[r][j];
            }
        }
        __syncthreads();
    }

    // ---------------- Phase C: causal online-softmax attention ----------------
    {
        const int w  = tid >> 6;                  // wave id 0..7
        const int tq = (w << 4) | (tid & 15);     // wave-contiguous t blocks
        const int h  = (tid >> 4) & 3;

        const float* qp = sq + h * 2052 + tq * 16;
        float qr[16];
        #pragma unroll
        for (int i = 0; i < 4; ++i) {
            float4 q4 = *reinterpret_cast<const float4*>(qp + i * 4);
            qr[i * 4 + 0] = q4.x; qr[i * 4 + 1] = q4.y;
            qr[i * 4 + 2] = q4.z; qr[i * 4 + 3] = q4.w;
        }

        float m = -1e30f, l = 0.0f;
        float y[16];
        #pragma unroll
        for (int i = 0; i < 16; ++i) y[i] = 0.0f;

        const float* kh = sk + h * 2052;
        const float* vh = sv + h * 2052;
        for (int s = 0; s <= tq; ++s) {
            const float* kp = kh + s * 16;
            float4 k0 = *reinterpret_cast<const float4*>(kp);
            float4 k1 = *reinterpret_cast<const float4*>(kp + 4);
            float4 k2 = *reinterpret_cast<const float4*>(kp + 8);
            float4 k3 = *reinterpret_cast<const float4*>(kp + 12);
            float d0 = qr[0] * k0.x + qr[1] * k0.y + qr[2]  * k0.z + qr[3]  * k0.w;
            float d1 = qr[4] * k1.x + qr[5] * k1.y + qr[6]  * k1.z + qr[7]  * k1.w;
            float d2 = qr[8] * k2.x + qr[9] * k2.y + qr[10] * k2.z + qr[11] * k2.w;
            float d3 = qr[12]* k3.x + qr[13]* k3.y + qr[14] * k3.z + qr[15] * k3.w;
            float sc = ((d0 + d1) + (d2 + d3)) * 0.25f;

            float mn   = fmaxf(m, sc);
            float corr = __expf(m - mn);
            float p    = __expf(sc - mn);
            l = l * corr + p;

            const float* vp = vh + s * 16;
            float4 v0 = *reinterpret_cast<const float4*>(vp);
            float4 v1 = *reinterpret_cast<const float4*>(vp + 4);
            float4 v2 = *reinterpret_cast<const float4*>(vp + 8);
            float4 v3 = *reinterpret_cast<const float4*>(vp + 12);
            y[0]  = y[0]  * corr + p * v0.x;  y[1]  = y[1]  * corr + p * v0.y;
            y[2]  = y[2]  * corr + p * v0.z;  y[3]  = y[3]  * corr + p * v0.w;
            y[4]  = y[4]  * corr + p * v1.x;  y[5]  = y[5]  * corr + p * v1.y;
            y[6]  = y[6]  * corr + p * v1.z;  y[7]  = y[7]  * corr + p * v1.w;
            y[8]  = y[8]  * corr + p * v2.x;  y[9]  = y[9]  * corr + p * v2.y;
            y[10] = y[10] * corr + p * v2.z;  y[11] = y[11] * corr + p * v2.w;
            y[12] = y[12] * corr + p * v3.x;  y[13] = y[13] * corr + p * v3.y;
            y[14] = y[14] * corr + p * v3.z;  y[15] = y[15] * corr + p * v3.w;
            m = mn;
        }

        float inv = 1.0f / l;
        float* yp = sx + tq * 65 + h * 16;     // sy aliases sx (x is dead)
        #pragma unroll
        for (int i = 0; i < 16; ++i) yp[i] = y[i] * inv;
    }

    // stage W_proj -> sW[64][64] (sW free after phase B's closing barrier)
    for (int i = tid; i < (64 * 64) / 4; i += NTH) {
        int k = i >> 4;
        int c = (i & 15) << 2;
        *reinterpret_cast<float4*>(sW + k * 64 + c) =
            *reinterpret_cast<const float4*>(Wp + k * 64 + c);
    }
    __syncthreads();   // sy writes + W_proj staging all visible

    // ---------------- Phase D: out = y @ Wp + bp ----------------
    {
        const int tr = tid >> 2;            // row 0..127
        const int c0 = (tid & 3) << 4;      // 0,16,32,48
        float accd[16];
        #pragma unroll
        for (int j = 0; j < 16; ++j) accd[j] = bp[c0 + j];

        for (int k = 0; k < 64; ++k) {
            float yv = sx[tr * 65 + k];
            const float* wrow = sW + k * 64 + c0;
            float4 w0 = *reinterpret_cast<const float4*>(wrow);
            float4 w1 = *reinterpret_cast<const float4*>(wrow + 4);
            float4 w2 = *reinterpret_cast<const float4*>(wrow + 8);
            float4 w3 = *reinterpret_cast<const float4*>(wrow + 12);
            accd[0]  = fmaf(yv, w0.x, accd[0]);  accd[1]  = fmaf(yv, w0.y, accd[1]);
            accd[2]  = fmaf(yv, w0.z, accd[2]);  accd[3]  = fmaf(yv, w0.w, accd[3]);
            accd[4]  = fmaf(yv, w1.x, accd[4]);  accd[5]  = fmaf(yv, w1.y, accd[5]);
            accd[6]  = fmaf(yv, w1.z, accd[6]);  accd[7]  = fmaf(yv, w1.w, accd[7]);
            accd[8]  = fmaf(yv, w2.x, accd[8]);  accd[9]  = fmaf(yv, w2.y, accd[9]);
            accd[10] = fmaf(yv, w2.z, accd[10]); accd[11] = fmaf(yv, w2.w, accd[11]);
            accd[12] = fmaf(yv, w3.x, accd[12]); accd[13] = fmaf(yv, w3.y, accd[13]);
            accd[14] = fmaf(yv, w3.z, accd[14]); accd[15] = fmaf(yv, w3.w, accd[15]);
        }

        float* op = out + (size_t)b * (TT * CCH) + tr * CCH + c0;
        *reinterpret_cast<float4*>(op)      = make_float4(accd[0],  accd[1],  accd[2],  accd[3]);
        *reinterpret_cast<float4*>(op + 4)  = make_float4(accd[4],  accd[5],  accd[6],  accd[7]);
        *reinterpret_cast<float4*>(op + 8)  = make_float4(accd[8],  accd[9],  accd[10], accd[11]);
        *reinterpret_cast<float4*>(op + 12) = make_float4(accd[12], accd[13], accd[14], accd[15]);
    }
}

extern "C" void kernel_launch(void* const* d_in, const int* in_sizes, int n_in,
                              void* d_out, int out_size, void* d_ws, size_t ws_size,
                              hipStream_t stream) {
    const float* x  = (const float*)d_in[0];
    const float* Wa = (const float*)d_in[1];
    const float* ba = (const float*)d_in[2];
    const float* Wp = (const float*)d_in[3];
    const float* bp = (const float*)d_in[4];
    float* out = (float*)d_out;

    const int B = in_sizes[0] / (TT * CCH);   // 1024
    const size_t lds_bytes = LDS_FLOATS * sizeof(float);

    // opt-in to >64KB dynamic LDS (idempotent, host-side, capture-safe)
    (void)hipFuncSetAttribute(reinterpret_cast<const void*>(csa_fused),
                              hipFuncAttributeMaxDynamicSharedMemorySize,
                              (int)lds_bytes);

    csa_fused<<<B, NTH, lds_bytes, stream>>>(x, Wa, ba, Wp, bp, out);
}

// Round 2
// 48.602 us; speedup vs baseline: 4.2195x; 4.2195x over previous
//
#include <hip/hip_runtime.h>
#include <hip/hip_fp16.h>

#define NTH 512

typedef __attribute__((ext_vector_type(8))) _Float16 f16x8;
typedef __attribute__((ext_vector_type(4))) float f32x4;

union U16x8 { uint4 u; f16x8 h; };

// two 8B LDS loads -> one f16x8 fragment
static __device__ __forceinline__ f16x8 ld2b64(const _Float16* p) {
    uint2 lo = *reinterpret_cast<const uint2*>(p);
    uint2 hi = *reinterpret_cast<const uint2*>(p + 4);
    U16x8 r; r.u = make_uint4(lo.x, lo.y, hi.x, hi.y);
    return r.h;
}
static __device__ __forceinline__ unsigned pk2(float a, float b) {
    union { __half2 h; unsigned u; } v;
    v.h = __floats2half2_rn(a, b);
    return v.u;
}

// LDS map (bytes):
//   [0,18432)      : phase B: sWaT [192][40] f16 (15360 B used)
//                    phase C/D: sO [128][72] f16 (18432 B) -- aliases sWaT
//   [18432,38912)  : sQ [4][128][20] f16   (q pre-scaled by 0.25)
//   [38912,59392)  : sK [4][128][20] f16
//   [59392,76288)  : sV [4][16][132] f16   (V transposed: [d][s])
#define LDS_BYTES 76288

__global__ __launch_bounds__(NTH, 4)
void csa_mfma(const float* __restrict__ x, const float* __restrict__ Wa,
              const float* __restrict__ ba, const float* __restrict__ Wp,
              const float* __restrict__ bp, float* __restrict__ out)
{
    extern __shared__ __align__(16) char lds[];
    _Float16* sWaT = reinterpret_cast<_Float16*>(lds);
    _Float16* sO   = reinterpret_cast<_Float16*>(lds);
    _Float16* sQ   = reinterpret_cast<_Float16*>(lds + 18432);
    _Float16* sK   = reinterpret_cast<_Float16*>(lds + 38912);
    _Float16* sV   = reinterpret_cast<_Float16*>(lds + 59392);

    const int b    = blockIdx.x;
    const int tid  = threadIdx.x;
    const int lane = tid & 63;
    const int w    = tid >> 6;    // wave 0..7
    const int lc   = lane & 15;
    const int lg   = lane >> 4;   // 0..3

    const float* __restrict__ xb = x + (size_t)b * 8192;

    // ================= Phase B: qkv = x @ Wa + ba =================
    // wave w owns M-tile w (rows t in [16w,16w+16)), all 12 N-tiles.
    // A-frag (x) straight from global, cvt to f16.
    f16x8 afr[2];
    {
        const float* xr = xb + (16 * w + lc) * 64 + 8 * lg;
        #pragma unroll
        for (int kk = 0; kk < 2; ++kk) {
            float4 a = *reinterpret_cast<const float4*>(xr + 32 * kk);
            float4 c = *reinterpret_cast<const float4*>(xr + 32 * kk + 4);
            f16x8 f;
            f[0] = (_Float16)a.x; f[1] = (_Float16)a.y; f[2] = (_Float16)a.z; f[3] = (_Float16)a.w;
            f[4] = (_Float16)c.x; f[5] = (_Float16)c.y; f[6] = (_Float16)c.z; f[7] = (_Float16)c.w;
            afr[kk] = f;
        }
    }

    f32x4 acc[12];
    #pragma unroll
    for (int n = 0; n < 12; ++n) {
        float bias = ba[16 * n + lc];
        acc[n] = (f32x4){bias, bias, bias, bias};
    }

    for (int kk = 0; kk < 2; ++kk) {
        __syncthreads();  // prior sWaT readers done (no-op on first iter)
        // stage Wa rows [32kk,32kk+32) transposed: sWaT[c][k_local]
        #pragma unroll
        for (int q = 0; q < 3; ++q) {
            int idx = tid + NTH * q;       // 0..1535 = 32 rows x 48 float4
            int r   = idx / 48;
            int c4  = (idx % 48) * 4;
            float4 v4 = *reinterpret_cast<const float4*>(Wa + (32 * kk + r) * 192 + c4);
            sWaT[(c4 + 0) * 40 + r] = (_Float16)v4.x;
            sWaT[(c4 + 1) * 40 + r] = (_Float16)v4.y;
            sWaT[(c4 + 2) * 40 + r] = (_Float16)v4.z;
            sWaT[(c4 + 3) * 40 + r] = (_Float16)v4.w;
        }
        __syncthreads();
        #pragma unroll
        for (int n = 0; n < 12; ++n) {
            // B-frag: col = 16n+lc, k = 8lg+j  (contiguous b128)
            f16x8 bfr = *reinterpret_cast<const f16x8*>(sWaT + (16 * n + lc) * 40 + 8 * lg);
            acc[n] = __builtin_amdgcn_mfma_f32_16x16x32_f16(afr[kk], bfr, acc[n], 0, 0, 0);
        }
    }

    // scatter q/k/v (D-frag: col=16n+lc, row=t=16w+4lg+j)
    #pragma unroll
    for (int n = 0; n < 12; ++n) {
        const int h = n & 3;
        const int kind = n >> 2;  // 0=q 1=k 2=v
        if (kind == 0) {
            #pragma unroll
            for (int j = 0; j < 4; ++j)
                sQ[h * 2560 + (16 * w + 4 * lg + j) * 20 + lc] = (_Float16)(acc[n][j] * 0.25f);
        } else if (kind == 1) {
            #pragma unroll
            for (int j = 0; j < 4; ++j)
                sK[h * 2560 + (16 * w + 4 * lg + j) * 20 + lc] = (_Float16)acc[n][j];
        } else {
            uint2 u;
            u.x = pk2(acc[n][0], acc[n][1]);
            u.y = pk2(acc[n][2], acc[n][3]);
            *reinterpret_cast<uint2*>(sV + h * 2112 + lc * 132 + 16 * w + 4 * lg) = u;
        }
    }
    __syncthreads();

    // ================= Phase C: causal flash attention =================
    // wave = (head h = w&3, t-half p = w>>2). Swapped QK^T: S^T = mfma(K,Q)
    // so softmax state is lane-local (lane&15 = t within tile).
    {
        const int h = w & 3;
        const int p = w >> 2;
        const _Float16* Qh = sQ + h * 2560;
        const _Float16* Kh = sK + h * 2560;
        const _Float16* Vh = sV + h * 2112;

        f16x8 qf[4];
        #pragma unroll
        for (int nn = 0; nn < 4; ++nn)
            qf[nn] = ld2b64(Qh + (16 * (4 * p + nn) + lc) * 20 + 8 * (lg & 1));

        f32x4 Ofr[4];
        float mrow[4], lrow[4];
        #pragma unroll
        for (int nn = 0; nn < 4; ++nn) {
            Ofr[nn] = (f32x4){0.f, 0.f, 0.f, 0.f};
            mrow[nn] = -1e30f; lrow[nn] = 0.f;
        }

        const f16x8 zf = {};
        const bool hihalf = (lg >= 2);
        const int idxA = (32 * (lg & 1) + lc) << 2;  // src lane g' = 2*(g&1)
        const int idxB = idxA + 64;                  // src lane g' = 2*(g&1)+1
        const int cmax = p ? 4 : 2;

        for (int c = 0; c < cmax; ++c) {
            f16x8 kf[2];
            #pragma unroll
            for (int i = 0; i < 2; ++i) {
                f16x8 t = ld2b64(Kh + (32 * c + 16 * i + lc) * 20 + 8 * (lg & 1));
                kf[i] = hihalf ? zf : t;  // K-dim 16 -> upper half of K=32 is zero
            }
            f16x8 vf = ld2b64(Vh + lc * 132 + 32 * c + 8 * lg);

            #pragma unroll
            for (int nn = 0; nn < 4; ++nn) {
                const int N = 4 * p + nn;
                if (2 * c > N) continue;  // wave-uniform causal tile skip
                f32x4 z4 = (f32x4){0.f, 0.f, 0.f, 0.f};
                f32x4 s0 = __builtin_amdgcn_mfma_f32_16x16x32_f16(kf[0], qf[nn], z4, 0, 0, 0);
                f32x4 s1 = __builtin_amdgcn_mfma_f32_16x16x32_f16(kf[1], qf[nn], z4, 0, 0, 0);
                const int t = 16 * N + lc;
                float pv[8];
                #pragma unroll
                for (int j = 0; j < 4; ++j) {
                    int sa = 32 * c + 4 * lg + j;      // s of s-tile 0
                    pv[j]     = (sa      <= t) ? s0[j] : -1e30f;
                    pv[4 + j] = (sa + 16 <= t) ? s1[j] : -1e30f;
                }
                float cm = fmaxf(fmaxf(fmaxf(pv[0], pv[1]), fmaxf(pv[2], pv[3])),
                                 fmaxf(fmaxf(pv[4], pv[5]), fmaxf(pv[6], pv[7])));
                cm = fmaxf(cm, __shfl_xor(cm, 16));
                cm = fmaxf(cm, __shfl_xor(cm, 32));
                float mnew = fmaxf(mrow[nn], cm);
                float corr = __expf(mrow[nn] - mnew);
                mrow[nn] = mnew;
                float ps = 0.f;
                #pragma unroll
                for (int e = 0; e < 8; ++e) { pv[e] = __expf(pv[e] - mnew); ps += pv[e]; }
                ps += __shfl_xor(ps, 16);
                ps += __shfl_xor(ps, 32);
                lrow[nn] = lrow[nn] * corr + ps;
                Ofr[nn] = Ofr[nn] * corr;

                // P^T (D-layout, k=4g+j) -> B-frag (k=8g+j) via packed bpermute
                int pk00 = (int)pk2(pv[0], pv[1]);   // s-tile0, j'=0,1
                int pk01 = (int)pk2(pv[2], pv[3]);   // s-tile0, j'=2,3
                int pk10 = (int)pk2(pv[4], pv[5]);   // s-tile1, j'=0,1
                int pk11 = (int)pk2(pv[6], pv[7]);   // s-tile1, j'=2,3
                int a0 = __builtin_amdgcn_ds_bpermute(idxA, pk00);
                int b0 = __builtin_amdgcn_ds_bpermute(idxA, pk10);
                int a1 = __builtin_amdgcn_ds_bpermute(idxA, pk01);
                int b1 = __builtin_amdgcn_ds_bpermute(idxA, pk11);
                int a2 = __builtin_amdgcn_ds_bpermute(idxB, pk00);
                int b2 = __builtin_amdgcn_ds_bpermute(idxB, pk10);
                int a3 = __builtin_amdgcn_ds_bpermute(idxB, pk01);
                int b3 = __builtin_amdgcn_ds_bpermute(idxB, pk11);
                U16x8 pu;
                pu.u = make_uint4((unsigned)(hihalf ? b0 : a0), (unsigned)(hihalf ? b1 : a1),
                                  (unsigned)(hihalf ? b2 : a2), (unsigned)(hihalf ? b3 : a3));
                Ofr[nn] = __builtin_amdgcn_mfma_f32_16x16x32_f16(vf, pu.h, Ofr[nn], 0, 0, 0);
            }
        }

        // normalize and write O[t][C] (aliases retired sWaT region)
        #pragma unroll
        for (int nn = 0; nn < 4; ++nn) {
            float inv = 1.0f / lrow[nn];
            int t = 16 * (4 * p + nn) + lc;
            uint2 u;
            u.x = pk2(Ofr[nn][0] * inv, Ofr[nn][1] * inv);
            u.y = pk2(Ofr[nn][2] * inv, Ofr[nn][3] * inv);
            *reinterpret_cast<uint2*>(sO + t * 72 + 16 * h + 4 * lg) = u;
        }
    }
    __syncthreads();

    // ================= Phase D: out = O @ Wp + bp =================
    // wave w: m-tile (c' block) = w>>1, n-tiles (t blocks) = [4(w&1), 4(w&1)+4)
    {
        const int m  = w >> 1;
        const int n0 = 4 * (w & 1);
        float4 bia = *reinterpret_cast<const float4*>(bp + 16 * m + 4 * lg);
        f32x4 dacc[4];
        #pragma unroll
        for (int i = 0; i < 4; ++i) dacc[i] = (f32x4){bia.x, bia.y, bia.z, bia.w};

        #pragma unroll
        for (int kk = 0; kk < 2; ++kk) {
            f16x8 af;  // Wp^T[c'][C]: A-frag row=c'=16m+lc, k=C=32kk+8lg+j
            #pragma unroll
            for (int j = 0; j < 8; ++j)
                af[j] = (_Float16)Wp[(32 * kk + 8 * lg + j) * 64 + 16 * m + lc];
            #pragma unroll
            for (int i = 0; i < 4; ++i) {
                f16x8 bf = *reinterpret_cast<const f16x8*>(sO + (16 * (n0 + i) + lc) * 72 + 32 * kk + 8 * lg);
                dacc[i] = __builtin_amdgcn_mfma_f32_16x16x32_f16(af, bf, dacc[i], 0, 0, 0);
            }
        }
        #pragma unroll
        for (int i = 0; i < 4; ++i) {
            int t = 16 * (n0 + i) + lc;
            *reinterpret_cast<float4*>(out + (size_t)b * 8192 + t * 64 + 16 * m + 4 * lg) =
                make_float4(dacc[i][0], dacc[i][1], dacc[i][2], dacc[i][3]);
        }
    }
}

extern "C" void kernel_launch(void* const* d_in, const int* in_sizes, int n_in,
                              void* d_out, int out_size, void* d_ws, size_t ws_size,
                              hipStream_t stream) {
    const float* x  = (const float*)d_in[0];
    const float* Wa = (const float*)d_in[1];
    const float* ba = (const float*)d_in[2];
    const float* Wp = (const float*)d_in[3];
    const float* bp = (const float*)d_in[4];
    float* out = (float*)d_out;

    const int B = in_sizes[0] / 8192;  // 1024

    (void)hipFuncSetAttribute(reinterpret_cast<const void*>(csa_mfma),
                              hipFuncAttributeMaxDynamicSharedMemorySize,
                              (int)LDS_BYTES);
    csa_mfma<<<B, NTH, LDS_BYTES, stream>>>(x, Wa, ba, Wp, bp, out);
}